// Round 20
// baseline (98.525 us; speedup 1.0000x reference)
//
#include <hip/hip_runtime.h>
#include <hip/hip_fp16.h>
#include <math.h>

#define D 30
#define FIXS 16777216.0f     // 2^24 fixed-point scale for degree weights
#define FIXA 1048576.0f      // 2^20 fixed-point scale for feature aggregation
#define BKT 128              // destination nodes per bucket
#define LGB 7
#define CHUNK 8192           // edges per chunk
#define CAP 4608             // per-bucket slab capacity (mean 4092 + 8 sigma)
#define ROWBITS 18
#define ROWMASK ((1u << ROWBITS) - 1)
#define MAXBKT 1024

// ---------------- Kernel 1: one-pass staged scatter ----------------
// Per chunk: LDS bucket count -> block scan -> ONE global atomicAdd per bucket to
// reserve slab space -> in-LDS counting sort -> coalesced write-out.
// Placement order across chunks is nondeterministic, but all downstream consumers
// are order-invariant integer accumulations -> output is deterministic.
__global__ __launch_bounds__(1024) void scatter1p_kernel(const int* __restrict__ row,
                                                         const int* __restrict__ col,
                                                         const float* __restrict__ ew,
                                                         unsigned* __restrict__ ecnt,
                                                         uint2* __restrict__ keysw,
                                                         int E, int nbkt) {
    __shared__ unsigned gcur[MAXBKT];     // slab offset reserved for this chunk
    __shared__ unsigned lofs[MAXBKT];     // within-chunk exclusive bucket offsets
    __shared__ unsigned lcnt[MAXBKT];     // counts / placement counters
    __shared__ unsigned sscan[1024];
    __shared__ uint2 st[CHUNK];           // 64 KB staged payloads (bucket-sorted)
    __shared__ unsigned short bkt[CHUNK]; // bucket id per staged slot
    const int t = threadIdx.x;
    for (int i = t; i < nbkt; i += 1024) lcnt[i] = 0;
    __syncthreads();

    const int e0 = blockIdx.x * CHUNK;
    const int e1 = min(e0 + CHUNK, E);
    const int cc = e1 - e0;               // chunk count
    const int nv = cc >> 2;
    const int4* c4 = (const int4*)(col + e0);

    // pass 1: within-chunk bucket counts
    for (int i = t; i < nv; i += 1024) {
        const int4 c = c4[i];
        atomicAdd(&lcnt[c.x >> LGB], 1u);
        atomicAdd(&lcnt[c.y >> LGB], 1u);
        atomicAdd(&lcnt[c.z >> LGB], 1u);
        atomicAdd(&lcnt[c.w >> LGB], 1u);
    }
    for (int e = e0 + (nv << 2) + t; e < e1; e += 1024) atomicAdd(&lcnt[col[e] >> LGB], 1u);
    __syncthreads();

    // block scan: lofs = exclusive scan of lcnt; reserve global slab space; reset lcnt
    {
        const unsigned v = (t < nbkt) ? lcnt[t] : 0u;
        sscan[t] = v;
        for (int off = 1; off < 1024; off <<= 1) {
            __syncthreads();
            const unsigned x = (t >= off) ? sscan[t - off] : 0u;
            __syncthreads();
            sscan[t] += x;
        }
        __syncthreads();
        if (t < nbkt) {
            lofs[t] = sscan[t] - v;
            gcur[t] = (v > 0) ? atomicAdd(&ecnt[t], v) : 0u;
            lcnt[t] = 0;
        }
    }
    __syncthreads();

    // pass 2: place edges into staged (bucket-sorted) LDS order
    const int4* r4 = (const int4*)(row + e0);
    const float4* w4 = (const float4*)(ew + e0);
    for (int i = t; i < nv; i += 1024) {
        const int4 c = c4[i];
        const int4 r = r4[i];
        const float4 w = w4[i];
#define PLACE(cx, rx, wx)                                                            \
        {                                                                            \
            const int b_ = (cx) >> LGB;                                              \
            const unsigned p_ = lofs[b_] + atomicAdd(&lcnt[b_], 1u);                 \
            st[p_] = make_uint2(((unsigned)((cx) & (BKT - 1)) << ROWBITS) |          \
                                (unsigned)(rx), __float_as_uint(wx));                \
            bkt[p_] = (unsigned short)b_;                                            \
        }
        PLACE(c.x, r.x, w.x)
        PLACE(c.y, r.y, w.y)
        PLACE(c.z, r.z, w.z)
        PLACE(c.w, r.w, w.w)
    }
    for (int e = e0 + (nv << 2) + t; e < e1; e += 1024) {
        const int cx = col[e];
        const int b_ = cx >> LGB;
        const unsigned p_ = lofs[b_] + atomicAdd(&lcnt[b_], 1u);
        st[p_] = make_uint2(((unsigned)(cx & (BKT - 1)) << ROWBITS) | (unsigned)row[e],
                            __float_as_uint(ew[e]));
        bkt[p_] = (unsigned short)b_;
    }
    __syncthreads();

    // pass 3: sorted write-out into per-bucket slabs (consecutive p -> consecutive addrs)
    for (int p = t; p < cc; p += 1024) {
        const int b_ = bkt[p];
        const unsigned off = gcur[b_] + ((unsigned)p - lofs[b_]);
        if (off < CAP)   // defensive clamp; statistically unreachable
            keysw[(size_t)b_ * CAP + off] = st[p];
    }
}

// ---------------- Kernel 2: per-bucket degree from slab edges -> dis ----------------
__global__ __launch_bounds__(512) void degdis_kernel(const unsigned* __restrict__ ecnt,
                                                     const uint2* __restrict__ keysw,
                                                     float* __restrict__ dis, int N) {
    __shared__ unsigned degf[BKT];
    const int t = threadIdx.x;
    if (t < BKT) degf[t] = 0;
    __syncthreads();
    const int b = blockIdx.x;
    const uint2* kbase = keysw + (size_t)b * CAP;
    const unsigned ne = min(ecnt[b], (unsigned)CAP);
    for (unsigned e = t; e < ne; e += 512) {
        const uint2 kw = kbase[e];
        atomicAdd(&degf[kw.x >> ROWBITS], (unsigned)(__uint_as_float(kw.y) * FIXS));
    }
    __syncthreads();
    const int n = b * BKT + t;
    if (t < BKT && n < N)
        dis[n] = rsqrtf((float)degf[t] * (1.0f / FIXS) + 1.0f);  // +1 = self-loop
}

// ---------------- Kernel 3: x = h@W; yp = half(x * dis), padded to 32 ----------------
__global__ __launch_bounds__(256) void gemm_kernel(const float* __restrict__ h,
                                                   const float* __restrict__ W,
                                                   const float* __restrict__ dis,
                                                   uint4* __restrict__ yp4, int N) {
    __shared__ float hs[256 * D];
    __shared__ float Ws[D * D];
    const int t = threadIdx.x;
    const int nb = blockIdx.x * 256;
    const int cnt = min(256, N - nb);
    const int total = cnt * D;

    for (int i = t; i < D * D; i += 256) Ws[i] = W[i];
    // vectorized h staging: base nb*120 B is 16B-aligned (nb multiple of 256)
    {
        const float4* h4 = (const float4*)(h + (size_t)nb * D);
        float4* hs4 = (float4*)hs;
        const int nf4 = total >> 2;
        for (int i = t; i < nf4; i += 256) hs4[i] = h4[i];
        for (int i = (nf4 << 2) + t; i < total; i += 256) hs[i] = h[(size_t)nb * D + i];
    }
    __syncthreads();

    float x[D];
    float dv = 0.f;
    if (t < cnt) {
#pragma unroll
        for (int j = 0; j < D; ++j) x[j] = 0.f;
#pragma unroll
        for (int k = 0; k < D; ++k) {
            const float hv = hs[t * D + k];
#pragma unroll
            for (int j = 0; j < D; ++j) x[j] += hv * Ws[k * D + j];
        }
        dv = dis[nb + t];
    }
    __syncthreads();
    __half* hsh = (__half*)hs;   // reuse LDS as half[256][32]
    if (t < cnt) {
#pragma unroll
        for (int j = 0; j < D; ++j) hsh[t * 32 + j] = __float2half_rn(x[j] * dv);
        hsh[t * 32 + 30] = __float2half_rn(0.f);
        hsh[t * 32 + 31] = __float2half_rn(0.f);
    }
    __syncthreads();
    const uint4* hv4 = (const uint4*)hs;
    for (int i = t; i < cnt * 4; i += 256) yp4[nb * 4 + i] = hv4[i];
}

// ---------------- Kernel 4: bucket aggregation, shfl-dedup keys + ILP-4 gathers ----------------
// acci element j of node loc lives at (loc<<5) + (j ^ (loc&31)) -> full 32-bank spread
__global__ __launch_bounds__(512) void aggmlp_kernel(const uint4* __restrict__ yp4,
                                                     const float* __restrict__ dis,
                                                     const unsigned* __restrict__ ecnt,
                                                     const uint2* __restrict__ keysw,
                                                     const float* __restrict__ convb,
                                                     const float* __restrict__ w1,
                                                     const float* __restrict__ b1,
                                                     const float* __restrict__ w2,
                                                     const float* __restrict__ b2,
                                                     const float* __restrict__ w3,
                                                     const float* __restrict__ b3,
                                                     const float* __restrict__ w4,
                                                     const float* __restrict__ b4,
                                                     float* __restrict__ out, int N) {
    __shared__ int acci[BKT * 32];   // fixed-point accumulator, 5-bit XOR swizzled (16 KB)
    __shared__ float cb[D];
    __shared__ float W1[300], B1[10], W2[100], B2[10], W3[100], B3[10], W4[10], B4v[1];
    const int t = threadIdx.x;
    if (t < D) cb[t] = convb[t];
    if (t < 300) W1[t] = w1[t];
    if (t < 100) W2[t] = w2[t];
    if (t >= 128 && t < 228) W3[t - 128] = w3[t - 128];
    if (t < 10) { B1[t] = b1[t]; B2[t] = b2[t]; B3[t] = b3[t]; W4[t] = w4[t]; }
    if (t == 0) B4v[0] = b4[0];

    const int b = blockIdx.x;
    const int nb = b * BKT;
    const int cnt = min(BKT, N - nb);

    // self-loop init: acc = fix(y_self)   (swizzled, no atomics needed)
    for (int i = t; i < cnt * 4; i += 512) {
        const int n = i >> 2, qq = i & 3;
        const uint4 v = yp4[(size_t)(nb + n) * 4 + qq];
        const __half2* hh = (const __half2*)&v;
        const float2 f0 = __half22float2(hh[0]);
        const float2 f1 = __half22float2(hh[1]);
        const float2 f2 = __half22float2(hh[2]);
        const float2 f3 = __half22float2(hh[3]);
        const int bo = n << 5, sw = n & 31, wb = qq << 3;
        acci[bo + ((wb + 0) ^ sw)] = __float2int_rn(f0.x * FIXA);
        acci[bo + ((wb + 1) ^ sw)] = __float2int_rn(f0.y * FIXA);
        acci[bo + ((wb + 2) ^ sw)] = __float2int_rn(f1.x * FIXA);
        acci[bo + ((wb + 3) ^ sw)] = __float2int_rn(f1.y * FIXA);
        acci[bo + ((wb + 4) ^ sw)] = __float2int_rn(f2.x * FIXA);
        acci[bo + ((wb + 5) ^ sw)] = __float2int_rn(f2.y * FIXA);
        acci[bo + ((wb + 6) ^ sw)] = __float2int_rn(f3.x * FIXA);
        acci[bo + ((wb + 7) ^ sw)] = __float2int_rn(f3.y * FIXA);
    }
    __syncthreads();

    const uint2* kbase = keysw + (size_t)b * CAP;
    const int ne = (int)min(ecnt[b], (unsigned)CAP);
    const int q = t & 3;          // fixed feature quad per thread
    const int eg0 = (t >> 2) << 2; // group's first edge offset within stripe (= (t&~3))

#define EDGE2(kx, ky, v)                                                             \
    {                                                                                \
        const float wf = __uint_as_float(ky) * FIXA;                                 \
        const __half2* hh = (const __half2*)&(v);                                    \
        const float2 f0 = __half22float2(hh[0]);                                     \
        const float2 f1 = __half22float2(hh[1]);                                     \
        const float2 f2 = __half22float2(hh[2]);                                     \
        const float2 f3 = __half22float2(hh[3]);                                     \
        const int loc = (int)((kx) >> ROWBITS);                                      \
        const int bo = loc << 5;                                                     \
        const int sw = loc & 31;                                                     \
        const int wb = q << 3;                                                       \
        atomicAdd(&acci[bo + ((wb + 0) ^ sw)], __float2int_rn(f0.x * wf));           \
        atomicAdd(&acci[bo + ((wb + 1) ^ sw)], __float2int_rn(f0.y * wf));           \
        atomicAdd(&acci[bo + ((wb + 2) ^ sw)], __float2int_rn(f1.x * wf));           \
        atomicAdd(&acci[bo + ((wb + 3) ^ sw)], __float2int_rn(f1.y * wf));           \
        atomicAdd(&acci[bo + ((wb + 4) ^ sw)], __float2int_rn(f2.x * wf));           \
        atomicAdd(&acci[bo + ((wb + 5) ^ sw)], __float2int_rn(f2.y * wf));           \
        atomicAdd(&acci[bo + ((wb + 6) ^ sw)], __float2int_rn(f3.x * wf));           \
        atomicAdd(&acci[bo + ((wb + 7) ^ sw)], __float2int_rn(f3.y * wf));           \
    }

    // 512-edge stripes: each lane loads ONE key (coalesced); 4-lane groups broadcast
    // their 4 keys via 64-bit shfl; 4 independent gathers per thread in flight.
    for (int base = 0; base < ne; base += 512) {
        const int myE = base + t;
        uint2 km = make_uint2(0u, 0u);
        if (myE < ne) km = kbase[myE];
        const unsigned long long kull =
            ((unsigned long long)km.y << 32) | (unsigned long long)km.x;
        const int l0 = t & ~3;   // shfl srcLane mods by 64 internally
        const unsigned long long ks0 = __shfl(kull, l0 + 0);
        const unsigned long long ks1 = __shfl(kull, l0 + 1);
        const unsigned long long ks2 = __shfl(kull, l0 + 2);
        const unsigned long long ks3 = __shfl(kull, l0 + 3);
        const unsigned kx0 = (unsigned)ks0, ky0 = (unsigned)(ks0 >> 32);
        const unsigned kx1 = (unsigned)ks1, ky1 = (unsigned)(ks1 >> 32);
        const unsigned kx2 = (unsigned)ks2, ky2 = (unsigned)(ks2 >> 32);
        const unsigned kx3 = (unsigned)ks3, ky3 = (unsigned)(ks3 >> 32);
        // 4 independent gathers (garbage lanes read row 0 -- valid memory)
        const uint4 v0 = yp4[(size_t)(kx0 & ROWMASK) * 4 + q];
        const uint4 v1 = yp4[(size_t)(kx1 & ROWMASK) * 4 + q];
        const uint4 v2 = yp4[(size_t)(kx2 & ROWMASK) * 4 + q];
        const uint4 v3 = yp4[(size_t)(kx3 & ROWMASK) * 4 + q];
        const int eg = base + eg0;
        if (eg + 0 < ne) EDGE2(kx0, ky0, v0)
        if (eg + 1 < ne) EDGE2(kx1, ky1, v1)
        if (eg + 2 < ne) EDGE2(kx2, ky2, v2)
        if (eg + 3 < ne) EDGE2(kx3, ky3, v3)
    }
    __syncthreads();

    if (t < cnt) {
        const int nn = nb + t;
        const float dv = dis[nn] * (1.0f / FIXA);   // fold fixed-point descale into dis
        const int bo = t << 5;
        const int sw = t & 31;
        float v[D];
#pragma unroll
        for (int j = 0; j < D; ++j)
            v[j] = fmaxf(dv * (float)acci[bo + (j ^ sw)] + cb[j], 0.f);
        float h1[10];
#pragma unroll
        for (int j = 0; j < 10; ++j) h1[j] = B1[j];
#pragma unroll
        for (int k = 0; k < D; ++k) {
            const float vv = v[k];
#pragma unroll
            for (int j = 0; j < 10; ++j) h1[j] += vv * W1[k * 10 + j];
        }
#pragma unroll
        for (int j = 0; j < 10; ++j) h1[j] = fmaxf(h1[j], 0.f);
        float h2[10];
#pragma unroll
        for (int j = 0; j < 10; ++j) h2[j] = B2[j];
#pragma unroll
        for (int k = 0; k < 10; ++k) {
            const float vv = h1[k];
#pragma unroll
            for (int j = 0; j < 10; ++j) h2[j] += vv * W2[k * 10 + j];
        }
#pragma unroll
        for (int j = 0; j < 10; ++j) h2[j] = fmaxf(h2[j], 0.f);
        float h3[10];
#pragma unroll
        for (int j = 0; j < 10; ++j) h3[j] = B3[j];
#pragma unroll
        for (int k = 0; k < 10; ++k) {
            const float vv = h2[k];
#pragma unroll
            for (int j = 0; j < 10; ++j) h3[j] += vv * W3[k * 10 + j];
        }
#pragma unroll
        for (int j = 0; j < 10; ++j) h3[j] = fmaxf(h3[j], 0.f);
        float z = B4v[0];
#pragma unroll
        for (int k = 0; k < 10; ++k) z += h3[k] * W4[k];
        out[nn] = 1.f / (1.f + expf(-z));
    }
}

extern "C" void kernel_launch(void* const* d_in, const int* in_sizes, int n_in,
                              void* d_out, int out_size, void* d_ws, size_t ws_size,
                              hipStream_t stream) {
    const float* h   = (const float*)d_in[0];
    const int*   ei  = (const int*)d_in[1];   // [2, E]: row = ei[0:E], col = ei[E:2E]
    const float* ew  = (const float*)d_in[2];
    const float* convW = (const float*)d_in[3];
    const float* convb = (const float*)d_in[4];
    const float* w1 = (const float*)d_in[5];
    const float* b1 = (const float*)d_in[6];
    const float* w2 = (const float*)d_in[7];
    const float* b2 = (const float*)d_in[8];
    const float* w3 = (const float*)d_in[9];
    const float* b3 = (const float*)d_in[10];
    const float* w4 = (const float*)d_in[11];
    const float* b4 = (const float*)d_in[12];
    float* out = (float*)d_out;

    const int N = in_sizes[0] / D;
    const int E = in_sizes[2];
    const int* row = ei;
    const int* col = ei + E;

    const int nbkt = (N + BKT - 1) >> LGB;        // 782 for N=100000
    const int nchunks = (E + CHUNK - 1) / CHUNK;  // 391
    const int nblk256 = (N + 255) / 256;          // gemm blocks

    // workspace: yp[N*32 half] | keysw[nbkt*CAP uint2] | dis[N] | ecnt[nbkt]
    __half* yp = (__half*)d_ws;
    uint2* keysw = (uint2*)(yp + (size_t)N * 32);
    float* dis = (float*)(keysw + (size_t)nbkt * CAP);
    unsigned* ecnt = (unsigned*)(dis + N);

    hipMemsetAsync(ecnt, 0, (size_t)nbkt * sizeof(unsigned), stream);

    scatter1p_kernel<<<nchunks, 1024, 0, stream>>>(row, col, ew, ecnt, keysw, E, nbkt);
    degdis_kernel<<<nbkt, 512, 0, stream>>>(ecnt, keysw, dis, N);
    gemm_kernel<<<nblk256, 256, 0, stream>>>(h, convW, dis, (uint4*)yp, N);
    aggmlp_kernel<<<nbkt, 512, 0, stream>>>((const uint4*)yp, dis, ecnt, keysw, convb,
                                            w1, b1, w2, b2, w3, b3, w4, b4, out, N);
}

// Round 21
// 94.367 us; speedup vs baseline: 1.0441x; 1.0441x over previous
//
#include <hip/hip_runtime.h>
#include <hip/hip_fp16.h>
#include <math.h>

#define D 30
#define FIXS 16777216.0f     // 2^24 fixed-point scale for degree weights
#define FIXA 1048576.0f      // 2^20 fixed-point scale for feature aggregation
#define BKT 128              // destination nodes per bucket
#define LGB 7
#define CHUNK 8192           // edges per chunk
#define CAP 4608             // per-bucket slab capacity (mean 4092 + 8 sigma)
#define ROWBITS 18
#define ROWMASK ((1u << ROWBITS) - 1)
#define MAXBKT 1024

// ---------------- Kernel 1: one-pass staged scatter ----------------
// Per chunk: LDS bucket count -> block scan -> ONE global atomicAdd per bucket to
// reserve slab space -> in-LDS counting sort -> coalesced write-out.
// Placement order across chunks is nondeterministic, but all downstream consumers
// are order-invariant integer accumulations -> output is deterministic.
__global__ __launch_bounds__(1024) void scatter1p_kernel(const int* __restrict__ row,
                                                         const int* __restrict__ col,
                                                         const float* __restrict__ ew,
                                                         unsigned* __restrict__ ecnt,
                                                         uint2* __restrict__ keysw,
                                                         int E, int nbkt) {
    __shared__ unsigned gcur[MAXBKT];     // slab offset reserved for this chunk
    __shared__ unsigned lofs[MAXBKT];     // within-chunk exclusive bucket offsets
    __shared__ unsigned lcnt[MAXBKT];     // counts / placement counters
    __shared__ unsigned sscan[1024];
    __shared__ uint2 st[CHUNK];           // 64 KB staged payloads (bucket-sorted)
    __shared__ unsigned short bkt[CHUNK]; // bucket id per staged slot
    const int t = threadIdx.x;
    for (int i = t; i < nbkt; i += 1024) lcnt[i] = 0;
    __syncthreads();

    const int e0 = blockIdx.x * CHUNK;
    const int e1 = min(e0 + CHUNK, E);
    const int cc = e1 - e0;               // chunk count
    const int nv = cc >> 2;
    const int4* c4 = (const int4*)(col + e0);

    // pass 1: within-chunk bucket counts
    for (int i = t; i < nv; i += 1024) {
        const int4 c = c4[i];
        atomicAdd(&lcnt[c.x >> LGB], 1u);
        atomicAdd(&lcnt[c.y >> LGB], 1u);
        atomicAdd(&lcnt[c.z >> LGB], 1u);
        atomicAdd(&lcnt[c.w >> LGB], 1u);
    }
    for (int e = e0 + (nv << 2) + t; e < e1; e += 1024) atomicAdd(&lcnt[col[e] >> LGB], 1u);
    __syncthreads();

    // block scan: lofs = exclusive scan of lcnt; reserve global slab space; reset lcnt
    {
        const unsigned v = (t < nbkt) ? lcnt[t] : 0u;
        sscan[t] = v;
        for (int off = 1; off < 1024; off <<= 1) {
            __syncthreads();
            const unsigned x = (t >= off) ? sscan[t - off] : 0u;
            __syncthreads();
            sscan[t] += x;
        }
        __syncthreads();
        if (t < nbkt) {
            lofs[t] = sscan[t] - v;
            gcur[t] = (v > 0) ? atomicAdd(&ecnt[t], v) : 0u;
            lcnt[t] = 0;
        }
    }
    __syncthreads();

    // pass 2: place edges into staged (bucket-sorted) LDS order
    const int4* r4 = (const int4*)(row + e0);
    const float4* w4 = (const float4*)(ew + e0);
    for (int i = t; i < nv; i += 1024) {
        const int4 c = c4[i];
        const int4 r = r4[i];
        const float4 w = w4[i];
#define PLACE(cx, rx, wx)                                                            \
        {                                                                            \
            const int b_ = (cx) >> LGB;                                              \
            const unsigned p_ = lofs[b_] + atomicAdd(&lcnt[b_], 1u);                 \
            st[p_] = make_uint2(((unsigned)((cx) & (BKT - 1)) << ROWBITS) |          \
                                (unsigned)(rx), __float_as_uint(wx));                \
            bkt[p_] = (unsigned short)b_;                                            \
        }
        PLACE(c.x, r.x, w.x)
        PLACE(c.y, r.y, w.y)
        PLACE(c.z, r.z, w.z)
        PLACE(c.w, r.w, w.w)
    }
    for (int e = e0 + (nv << 2) + t; e < e1; e += 1024) {
        const int cx = col[e];
        const int b_ = cx >> LGB;
        const unsigned p_ = lofs[b_] + atomicAdd(&lcnt[b_], 1u);
        st[p_] = make_uint2(((unsigned)(cx & (BKT - 1)) << ROWBITS) | (unsigned)row[e],
                            __float_as_uint(ew[e]));
        bkt[p_] = (unsigned short)b_;
    }
    __syncthreads();

    // pass 3: sorted write-out into per-bucket slabs (consecutive p -> consecutive addrs)
    for (int p = t; p < cc; p += 1024) {
        const int b_ = bkt[p];
        const unsigned off = gcur[b_] + ((unsigned)p - lofs[b_]);
        if (off < CAP)   // defensive clamp; statistically unreachable
            keysw[(size_t)b_ * CAP + off] = st[p];
    }
}

// ---------------- Kernel 2: per-bucket degree from slab edges -> dis ----------------
__global__ __launch_bounds__(512) void degdis_kernel(const unsigned* __restrict__ ecnt,
                                                     const uint2* __restrict__ keysw,
                                                     float* __restrict__ dis, int N) {
    __shared__ unsigned degf[BKT];
    const int t = threadIdx.x;
    if (t < BKT) degf[t] = 0;
    __syncthreads();
    const int b = blockIdx.x;
    const uint2* kbase = keysw + (size_t)b * CAP;
    const unsigned ne = min(ecnt[b], (unsigned)CAP);
    for (unsigned e = t; e < ne; e += 512) {
        const uint2 kw = kbase[e];
        atomicAdd(&degf[kw.x >> ROWBITS], (unsigned)(__uint_as_float(kw.y) * FIXS));
    }
    __syncthreads();
    const int n = b * BKT + t;
    if (t < BKT && n < N)
        dis[n] = rsqrtf((float)degf[t] * (1.0f / FIXS) + 1.0f);  // +1 = self-loop
}

// ---------------- Kernel 3: x = h@W; yp = half(x * dis), padded to 32 ----------------
__global__ __launch_bounds__(256) void gemm_kernel(const float* __restrict__ h,
                                                   const float* __restrict__ W,
                                                   const float* __restrict__ dis,
                                                   uint4* __restrict__ yp4, int N) {
    __shared__ float hs[256 * D];
    __shared__ float Ws[D * D];
    const int t = threadIdx.x;
    const int nb = blockIdx.x * 256;
    const int cnt = min(256, N - nb);
    const int total = cnt * D;

    for (int i = t; i < D * D; i += 256) Ws[i] = W[i];
    // vectorized h staging: base nb*120 B is 16B-aligned (nb multiple of 256)
    {
        const float4* h4 = (const float4*)(h + (size_t)nb * D);
        float4* hs4 = (float4*)hs;
        const int nf4 = total >> 2;
        for (int i = t; i < nf4; i += 256) hs4[i] = h4[i];
        for (int i = (nf4 << 2) + t; i < total; i += 256) hs[i] = h[(size_t)nb * D + i];
    }
    __syncthreads();

    float x[D];
    float dv = 0.f;
    if (t < cnt) {
#pragma unroll
        for (int j = 0; j < D; ++j) x[j] = 0.f;
#pragma unroll
        for (int k = 0; k < D; ++k) {
            const float hv = hs[t * D + k];
#pragma unroll
            for (int j = 0; j < D; ++j) x[j] += hv * Ws[k * D + j];
        }
        dv = dis[nb + t];
    }
    __syncthreads();
    __half* hsh = (__half*)hs;   // reuse LDS as half[256][32]
    if (t < cnt) {
#pragma unroll
        for (int j = 0; j < D; ++j) hsh[t * 32 + j] = __float2half_rn(x[j] * dv);
        hsh[t * 32 + 30] = __float2half_rn(0.f);
        hsh[t * 32 + 31] = __float2half_rn(0.f);
    }
    __syncthreads();
    const uint4* hv4 = (const uint4*)hs;
    for (int i = t; i < cnt * 4; i += 256) yp4[nb * 4 + i] = hv4[i];
}

// ---------------- Kernel 4: bucket aggregation via native int LDS atomics + fused MLP ----------------
// acci element j of node loc lives at (loc<<5) + (j ^ (loc&31)) -> full 32-bank spread
__global__ __launch_bounds__(512) void aggmlp_kernel(const uint4* __restrict__ yp4,
                                                     const float* __restrict__ dis,
                                                     const unsigned* __restrict__ ecnt,
                                                     const uint2* __restrict__ keysw,
                                                     const float* __restrict__ convb,
                                                     const float* __restrict__ w1,
                                                     const float* __restrict__ b1,
                                                     const float* __restrict__ w2,
                                                     const float* __restrict__ b2,
                                                     const float* __restrict__ w3,
                                                     const float* __restrict__ b3,
                                                     const float* __restrict__ w4,
                                                     const float* __restrict__ b4,
                                                     float* __restrict__ out, int N) {
    __shared__ int acci[BKT * 32];   // fixed-point accumulator, 5-bit XOR swizzled (16 KB)
    __shared__ float cb[D];
    __shared__ float W1[300], B1[10], W2[100], B2[10], W3[100], B3[10], W4[10], B4v[1];
    const int t = threadIdx.x;
    if (t < D) cb[t] = convb[t];
    if (t < 300) W1[t] = w1[t];
    if (t < 100) W2[t] = w2[t];
    if (t >= 128 && t < 228) W3[t - 128] = w3[t - 128];
    if (t < 10) { B1[t] = b1[t]; B2[t] = b2[t]; B3[t] = b3[t]; W4[t] = w4[t]; }
    if (t == 0) B4v[0] = b4[0];

    const int b = blockIdx.x;
    const int nb = b * BKT;
    const int cnt = min(BKT, N - nb);

    // self-loop init: acc = fix(y_self)   (swizzled, no atomics needed)
    for (int i = t; i < cnt * 4; i += 512) {
        const int n = i >> 2, qq = i & 3;
        const uint4 v = yp4[(size_t)(nb + n) * 4 + qq];
        const __half2* hh = (const __half2*)&v;
        const float2 f0 = __half22float2(hh[0]);
        const float2 f1 = __half22float2(hh[1]);
        const float2 f2 = __half22float2(hh[2]);
        const float2 f3 = __half22float2(hh[3]);
        const int bo = n << 5, sw = n & 31, wb = qq << 3;
        acci[bo + ((wb + 0) ^ sw)] = __float2int_rn(f0.x * FIXA);
        acci[bo + ((wb + 1) ^ sw)] = __float2int_rn(f0.y * FIXA);
        acci[bo + ((wb + 2) ^ sw)] = __float2int_rn(f1.x * FIXA);
        acci[bo + ((wb + 3) ^ sw)] = __float2int_rn(f1.y * FIXA);
        acci[bo + ((wb + 4) ^ sw)] = __float2int_rn(f2.x * FIXA);
        acci[bo + ((wb + 5) ^ sw)] = __float2int_rn(f2.y * FIXA);
        acci[bo + ((wb + 6) ^ sw)] = __float2int_rn(f3.x * FIXA);
        acci[bo + ((wb + 7) ^ sw)] = __float2int_rn(f3.y * FIXA);
    }
    __syncthreads();

    const uint2* kbase = keysw + (size_t)b * CAP;
    const int ne = (int)min(ecnt[b], (unsigned)CAP);
    const int m = ne * 4;   // 4 lanes per edge

#define EDGE(kw, q)                                                                  \
    {                                                                                \
        const float wf = __uint_as_float((kw).y) * FIXA;                             \
        const uint4 v = yp4[(size_t)((kw).x & ROWMASK) * 4 + (q)];                   \
        const __half2* hh = (const __half2*)&v;                                      \
        const float2 f0 = __half22float2(hh[0]);                                     \
        const float2 f1 = __half22float2(hh[1]);                                     \
        const float2 f2 = __half22float2(hh[2]);                                     \
        const float2 f3 = __half22float2(hh[3]);                                     \
        const int loc = (int)((kw).x >> ROWBITS);                                    \
        const int bo = loc << 5;                                                     \
        const int sw = loc & 31;                                                     \
        const int wb = (q) << 3;                                                     \
        atomicAdd(&acci[bo + ((wb + 0) ^ sw)], __float2int_rn(f0.x * wf));           \
        atomicAdd(&acci[bo + ((wb + 1) ^ sw)], __float2int_rn(f0.y * wf));           \
        atomicAdd(&acci[bo + ((wb + 2) ^ sw)], __float2int_rn(f1.x * wf));           \
        atomicAdd(&acci[bo + ((wb + 3) ^ sw)], __float2int_rn(f1.y * wf));           \
        atomicAdd(&acci[bo + ((wb + 4) ^ sw)], __float2int_rn(f2.x * wf));           \
        atomicAdd(&acci[bo + ((wb + 5) ^ sw)], __float2int_rn(f2.y * wf));           \
        atomicAdd(&acci[bo + ((wb + 6) ^ sw)], __float2int_rn(f3.x * wf));           \
        atomicAdd(&acci[bo + ((wb + 7) ^ sw)], __float2int_rn(f3.y * wf));           \
    }

    for (int i = t; i < m; i += 1024) {
        const int iB = i + 512;
        const uint2 kwA = kbase[i >> 2];
        const int qA = i & 3;
        if (iB < m) {
            const uint2 kwB = kbase[iB >> 2];
            const int qB = iB & 3;
            EDGE(kwA, qA)
            EDGE(kwB, qB)
        } else {
            EDGE(kwA, qA)
        }
    }
    __syncthreads();

    if (t < cnt) {
        const int nn = nb + t;
        const float dv = dis[nn] * (1.0f / FIXA);   // fold fixed-point descale into dis
        const int bo = t << 5;
        const int sw = t & 31;
        float v[D];
#pragma unroll
        for (int j = 0; j < D; ++j)
            v[j] = fmaxf(dv * (float)acci[bo + (j ^ sw)] + cb[j], 0.f);
        float h1[10];
#pragma unroll
        for (int j = 0; j < 10; ++j) h1[j] = B1[j];
#pragma unroll
        for (int k = 0; k < D; ++k) {
            const float vv = v[k];
#pragma unroll
            for (int j = 0; j < 10; ++j) h1[j] += vv * W1[k * 10 + j];
        }
#pragma unroll
        for (int j = 0; j < 10; ++j) h1[j] = fmaxf(h1[j], 0.f);
        float h2[10];
#pragma unroll
        for (int j = 0; j < 10; ++j) h2[j] = B2[j];
#pragma unroll
        for (int k = 0; k < 10; ++k) {
            const float vv = h1[k];
#pragma unroll
            for (int j = 0; j < 10; ++j) h2[j] += vv * W2[k * 10 + j];
        }
#pragma unroll
        for (int j = 0; j < 10; ++j) h2[j] = fmaxf(h2[j], 0.f);
        float h3[10];
#pragma unroll
        for (int j = 0; j < 10; ++j) h3[j] = B3[j];
#pragma unroll
        for (int k = 0; k < 10; ++k) {
            const float vv = h2[k];
#pragma unroll
            for (int j = 0; j < 10; ++j) h3[j] += vv * W3[k * 10 + j];
        }
#pragma unroll
        for (int j = 0; j < 10; ++j) h3[j] = fmaxf(h3[j], 0.f);
        float z = B4v[0];
#pragma unroll
        for (int k = 0; k < 10; ++k) z += h3[k] * W4[k];
        out[nn] = 1.f / (1.f + expf(-z));
    }
}

extern "C" void kernel_launch(void* const* d_in, const int* in_sizes, int n_in,
                              void* d_out, int out_size, void* d_ws, size_t ws_size,
                              hipStream_t stream) {
    const float* h   = (const float*)d_in[0];
    const int*   ei  = (const int*)d_in[1];   // [2, E]: row = ei[0:E], col = ei[E:2E]
    const float* ew  = (const float*)d_in[2];
    const float* convW = (const float*)d_in[3];
    const float* convb = (const float*)d_in[4];
    const float* w1 = (const float*)d_in[5];
    const float* b1 = (const float*)d_in[6];
    const float* w2 = (const float*)d_in[7];
    const float* b2 = (const float*)d_in[8];
    const float* w3 = (const float*)d_in[9];
    const float* b3 = (const float*)d_in[10];
    const float* w4 = (const float*)d_in[11];
    const float* b4 = (const float*)d_in[12];
    float* out = (float*)d_out;

    const int N = in_sizes[0] / D;
    const int E = in_sizes[2];
    const int* row = ei;
    const int* col = ei + E;

    const int nbkt = (N + BKT - 1) >> LGB;        // 782 for N=100000
    const int nchunks = (E + CHUNK - 1) / CHUNK;  // 391
    const int nblk256 = (N + 255) / 256;          // gemm blocks

    // workspace: yp[N*32 half] | keysw[nbkt*CAP uint2] | dis[N] | ecnt[nbkt]
    __half* yp = (__half*)d_ws;
    uint2* keysw = (uint2*)(yp + (size_t)N * 32);
    float* dis = (float*)(keysw + (size_t)nbkt * CAP);
    unsigned* ecnt = (unsigned*)(dis + N);

    hipMemsetAsync(ecnt, 0, (size_t)nbkt * sizeof(unsigned), stream);

    scatter1p_kernel<<<nchunks, 1024, 0, stream>>>(row, col, ew, ecnt, keysw, E, nbkt);
    degdis_kernel<<<nbkt, 512, 0, stream>>>(ecnt, keysw, dis, N);
    gemm_kernel<<<nblk256, 256, 0, stream>>>(h, convW, dis, (uint4*)yp, N);
    aggmlp_kernel<<<nbkt, 512, 0, stream>>>((const uint4*)yp, dis, ecnt, keysw, convb,
                                            w1, b1, w2, b2, w3, b3, w4, b4, out, N);
}